// Round 6
// baseline (266.794 us; speedup 1.0000x reference)
//
#include <hip/hip_runtime.h>

// Problem constants (match reference)
#define BB 2
#define CC 64
#define HH 512
#define WW 512
#define NN 4096
#define KK 5
#define HWp (HH * WW)

// ---------------------------------------------------------------------------
// Pass 1: gather sampled feature vectors into compact [B][N][C] buffers.
// wave = (sel, b, point-group g, channel-chunk of 16). lane = point.
//  - 16 independent strided gathers per lane in flight (latency hiding)
//  - lane's 16 results -> four float4 stores to ONE 64 B line (coalesced)
//  - lane addresses within one load have random low bits (lin) -> requests
//    spread across HBM channels / L2 banks
//  - feature reads are NONTEMPORAL: single-use random lines must not evict
//    the 4 MB Fr/Fo buffers from the 4 MiB/XCD L2 (the loss pass re-reads
//    Fr/Fo 7x; keeping them L2-resident is worth more than caching streams)
//  - also zeroes out[0]; kernel-boundary writeback makes it visible to the
//    loss pass's atomics (device coherence point)
// NOTE (round-4 post-mortem): never use per-block agent-scope acq/rel on
// gfx950 — each pair costs a full L2 writeback/invalidate (non-coherent
// per-XCD L2s); 2048 of them cost +46 us. Plain atomicAdd is a per-op RMW
// at the coherence point and is cheap (round 1: 8192 of them, no issue).
// ---------------------------------------------------------------------------
__global__ __launch_bounds__(256) void gather_kernel(
    const float* __restrict__ inputs_ref,
    const float* __restrict__ inputs_other,
    const int*   __restrict__ inds_ref,
    const int*   __restrict__ inds_other,
    float*       __restrict__ Fr,      // [B][N][C]
    float*       __restrict__ Fo,      // [B][N][C]
    float*       __restrict__ out)
{
    if (blockIdx.x == 0 && threadIdx.x == 0) out[0] = 0.0f;

    const int lane = threadIdx.x & 63;
    int w = (blockIdx.x * 256 + threadIdx.x) >> 6;   // wave id, 0..1023
    const int chunk = w & 3;  w >>= 2;   // 4 chunks of 16 channels
    const int g     = w & 63; w >>= 6;   // N/64 = 64 point groups
    const int b     = w & 1;  w >>= 1;   // B = 2
    const int sel   = w;                 // 0 = ref, 1 = other

    const int i = g * 64 + lane;
    const int* ind = (sel ? inds_other : inds_ref) + b * 2 * NN;
    const int lin = HH * ind[NN + i] + ind[i];       // H*y + x

    const float* src = (sel ? inputs_other : inputs_ref)
                       + (size_t)b * CC * HWp
                       + (size_t)chunk * 16 * HWp
                       + lin;
    float v[16];
#pragma unroll
    for (int cc = 0; cc < 16; ++cc)
        v[cc] = __builtin_nontemporal_load(src + (size_t)cc * HWp);

    float* dst = (sel ? Fo : Fr) + (size_t)(b * NN + i) * CC + chunk * 16;
#pragma unroll
    for (int q = 0; q < 4; ++q)
        ((float4*)dst)[q] = make_float4(v[4*q], v[4*q+1], v[4*q+2], v[4*q+3]);
}

// ---------------------------------------------------------------------------
// Pass 2: one wave per match point, lane = channel. All 7 feature vectors are
// contiguous 256 B reads from the compact L2-resident buffers (the 5 mismatch
// vectors are re-gathers of Fo at partner points j = rand_inds[i][k]).
// One plain device-scope atomicAdd per block (2048 total) -> out[0]; no
// third dispatch, no partials round-trip.
// ---------------------------------------------------------------------------
__global__ __launch_bounds__(256) void loss_kernel(
    const float* __restrict__ Fr,
    const float* __restrict__ Fo,
    const float* __restrict__ weights,
    const int*   __restrict__ inds_ref,
    const int*   __restrict__ rand_inds,
    float*       __restrict__ out)
{
    const int tid  = threadIdx.x;
    const int lane = tid & 63;
    const int wave = tid >> 6;                 // 4 waves / block
    const int gidx = blockIdx.x * 4 + wave;    // point index in [0, B*N)
    const int b = gidx / NN;
    const int i = gidx - b * NN;

    const int* ir = inds_ref + b * 2 * NN;     // x at [i], y at [NN+i]
    const int xr = ir[i];
    const int yr = ir[NN + i];
    const int* rj = rand_inds + (size_t)(b * NN + i) * KK;

    const float fr = Fr[(size_t)(b * NN + i) * CC + lane];
    const float fo = Fo[(size_t)(b * NN + i) * CC + lane];

    float s[1 + KK];
    float dist[KK];
    { const float d = fr - fo; s[0] = d * d; }
#pragma unroll
    for (int k = 0; k < KK; ++k) {
        const int j = rj[k];                               // wave-uniform
        const float fm = Fo[(size_t)(b * NN + j) * CC + lane];
        const float t = fr - fm;
        s[1 + k] = t * t;
        const float dx = (float)(xr - ir[j]);
        const float dy = (float)(yr - ir[NN + j]);
        dist[k] = sqrtf(dx * dx + dy * dy);
    }

    // 64-lane sum reductions for the 6 squared feature distances
#pragma unroll
    for (int r = 0; r < 1 + KK; ++r) {
        float v = s[r];
#pragma unroll
        for (int off = 32; off > 0; off >>= 1)
            v += __shfl_xor(v, off, 64);
        s[r] = v;
    }

    __shared__ float part[4];
    if (lane == 0) {
        const float max_distance = 724.07734f;   // sqrt(512^2+512^2)
        const float thr_nomatch  = 16.0f;        // 0.5^2 * C
        float acc = weights[b * NN + i] * fmaxf(s[0], 0.0f);
#pragma unroll
        for (int k = 0; k < KK; ++k) {
            // w_mm = -NON_MATCH_WEIGHT * d / max_dist / K, weight==K==5
            acc += (-dist[k] / max_distance) * fminf(s[1 + k], thr_nomatch);
        }
        part[wave] = acc * (1.0f / (float)((KK + 1) * NN));
    }
    __syncthreads();
    if (tid == 0)
        atomicAdd(out, part[0] + part[1] + part[2] + part[3]);
}

extern "C" void kernel_launch(void* const* d_in, const int* in_sizes, int n_in,
                              void* d_out, int out_size, void* d_ws, size_t ws_size,
                              hipStream_t stream) {
    const float* inputs_ref   = (const float*)d_in[0];
    const float* inputs_other = (const float*)d_in[1];
    const float* weights      = (const float*)d_in[2];
    const int*   inds_ref     = (const int*)d_in[3];
    const int*   inds_other   = (const int*)d_in[4];
    const int*   rand_inds    = (const int*)d_in[5];
    float* out = (float*)d_out;

    // workspace layout: Fr [B][N][C], Fo [B][N][C] (2 MB each)
    float* Fr = (float*)d_ws;
    float* Fo = Fr + (size_t)BB * NN * CC;

    // pass 1: 2(sel)*2(b)*64(g)*4(chunk) = 1024 waves -> 256 blocks
    //         (also zeroes out[0] for pass 2's atomics)
    gather_kernel<<<256, 256, 0, stream>>>(
        inputs_ref, inputs_other, inds_ref, inds_other, Fr, Fo, out);

    // pass 2: B*N = 8192 waves -> 2048 blocks, one atomicAdd per block
    loss_kernel<<<2048, 256, 0, stream>>>(
        Fr, Fo, weights, inds_ref, rand_inds, out);
}

// Round 7
// 247.113 us; speedup vs baseline: 1.0796x; 1.0796x over previous
//
#include <hip/hip_runtime.h>

// Problem constants (match reference)
#define BB 2
#define CC 64
#define HH 512
#define WW 512
#define NN 4096
#define KK 5
#define HWp (HH * WW)

// ---------------------------------------------------------------------------
// FINAL STRUCTURE (round-5 winner, re-confirmed):
//   gather (256 blk) -> loss (2048 blk, per-block partial) -> reduce (1 blk)
// Post-mortems that prove the alternatives lose on gfx950:
//  - round 4: per-block agent-scope release/acquire (last-block-done) costs a
//    full L2 writeback/invalidate per pair on non-coherent per-XCD L2s:
//    +46 us.
//  - round 6: 2048 same-address device-scope float atomicAdds serialize at
//    the coherence point (~300+ cyc each, cross-XCD): +21 us.
//  => plain extra dispatch + disjoint partial lines is the cheap path.
// ---------------------------------------------------------------------------

// ---------------------------------------------------------------------------
// Pass 1: gather sampled feature vectors into compact [B][N][C] buffers.
// wave = (sel, b, point-group g, channel-chunk of 16). lane = point.
//  - 16 independent strided gathers per lane in flight (latency hiding)
//  - lane's 16 results -> four float4 stores to ONE 64 B line (coalesced)
//  - lane addresses within one load have random low bits (lin) -> requests
//    spread across HBM channels / L2 banks (round-1 fix: lane=channel put
//    all 64 lanes 1 MiB apart = one channel+set = serialization, 20% BW)
//  - feature reads are NONTEMPORAL: single-use random lines must not evict
//    the 4 MB Fr/Fo buffers from the 4 MiB/XCD L2 (the loss pass re-reads
//    Fr/Fo 7x; keeping them L2-resident bought ~14 us in round 5)
// ---------------------------------------------------------------------------
__global__ __launch_bounds__(256) void gather_kernel(
    const float* __restrict__ inputs_ref,
    const float* __restrict__ inputs_other,
    const int*   __restrict__ inds_ref,
    const int*   __restrict__ inds_other,
    float*       __restrict__ Fr,      // [B][N][C]
    float*       __restrict__ Fo)      // [B][N][C]
{
    const int lane = threadIdx.x & 63;
    int w = (blockIdx.x * 256 + threadIdx.x) >> 6;   // wave id, 0..1023
    const int chunk = w & 3;  w >>= 2;   // 4 chunks of 16 channels
    const int g     = w & 63; w >>= 6;   // N/64 = 64 point groups
    const int b     = w & 1;  w >>= 1;   // B = 2
    const int sel   = w;                 // 0 = ref, 1 = other

    const int i = g * 64 + lane;
    const int* ind = (sel ? inds_other : inds_ref) + b * 2 * NN;
    const int lin = HH * ind[NN + i] + ind[i];       // H*y + x

    const float* src = (sel ? inputs_other : inputs_ref)
                       + (size_t)b * CC * HWp
                       + (size_t)chunk * 16 * HWp
                       + lin;
    float v[16];
#pragma unroll
    for (int cc = 0; cc < 16; ++cc)
        v[cc] = __builtin_nontemporal_load(src + (size_t)cc * HWp);

    float* dst = (sel ? Fo : Fr) + (size_t)(b * NN + i) * CC + chunk * 16;
#pragma unroll
    for (int q = 0; q < 4; ++q)
        ((float4*)dst)[q] = make_float4(v[4*q], v[4*q+1], v[4*q+2], v[4*q+3]);
}

// ---------------------------------------------------------------------------
// Pass 2: one wave per match point, lane = channel. All 7 feature vectors are
// contiguous 256 B reads from the compact L2-resident buffers (the 5 mismatch
// vectors are re-gathers of Fo at partner points j = rand_inds[i][k] — this
// removed 5/7 of the strided HBM gathers vs the naive formulation).
// Per-block partial written to a distinct ws line (no atomics, no fences).
// ---------------------------------------------------------------------------
__global__ __launch_bounds__(256) void loss_kernel(
    const float* __restrict__ Fr,
    const float* __restrict__ Fo,
    const float* __restrict__ weights,
    const int*   __restrict__ inds_ref,
    const int*   __restrict__ rand_inds,
    float*       __restrict__ partials)  // [gridDim.x]
{
    const int tid  = threadIdx.x;
    const int lane = tid & 63;
    const int wave = tid >> 6;                 // 4 waves / block
    const int gidx = blockIdx.x * 4 + wave;    // point index in [0, B*N)
    const int b = gidx / NN;
    const int i = gidx - b * NN;

    const int* ir = inds_ref + b * 2 * NN;     // x at [i], y at [NN+i]
    const int xr = ir[i];
    const int yr = ir[NN + i];
    const int* rj = rand_inds + (size_t)(b * NN + i) * KK;

    const float fr = Fr[(size_t)(b * NN + i) * CC + lane];
    const float fo = Fo[(size_t)(b * NN + i) * CC + lane];

    float s[1 + KK];
    float dist[KK];
    { const float d = fr - fo; s[0] = d * d; }
#pragma unroll
    for (int k = 0; k < KK; ++k) {
        const int j = rj[k];                               // wave-uniform
        const float fm = Fo[(size_t)(b * NN + j) * CC + lane];
        const float t = fr - fm;
        s[1 + k] = t * t;
        const float dx = (float)(xr - ir[j]);
        const float dy = (float)(yr - ir[NN + j]);
        dist[k] = sqrtf(dx * dx + dy * dy);
    }

    // 64-lane sum reductions for the 6 squared feature distances
#pragma unroll
    for (int r = 0; r < 1 + KK; ++r) {
        float v = s[r];
#pragma unroll
        for (int off = 32; off > 0; off >>= 1)
            v += __shfl_xor(v, off, 64);
        s[r] = v;
    }

    __shared__ float part[4];
    if (lane == 0) {
        const float max_distance = 724.07734f;   // sqrt(512^2+512^2)
        const float thr_nomatch  = 16.0f;        // 0.5^2 * C
        float acc = weights[b * NN + i] * fmaxf(s[0], 0.0f);
#pragma unroll
        for (int k = 0; k < KK; ++k) {
            // w_mm = -NON_MATCH_WEIGHT * d / max_dist / K, weight==K==5
            acc += (-dist[k] / max_distance) * fminf(s[1 + k], thr_nomatch);
        }
        part[wave] = acc * (1.0f / (float)((KK + 1) * NN));
    }
    __syncthreads();
    if (tid == 0)
        partials[blockIdx.x] = part[0] + part[1] + part[2] + part[3];
}

// ---------------------------------------------------------------------------
// Final: one block reduces the 2048 per-block partials and writes out[0]
// (overwrites the harness's 0xAA poison; no zero kernel needed).
// ---------------------------------------------------------------------------
__global__ __launch_bounds__(256) void reduce_kernel(
    const float* __restrict__ partials, int n, float* __restrict__ out)
{
    const int tid = threadIdx.x;
    float v = 0.0f;
    for (int idx = tid; idx < n; idx += 256)
        v += partials[idx];
#pragma unroll
    for (int off = 32; off > 0; off >>= 1)
        v += __shfl_xor(v, off, 64);
    __shared__ float part[4];
    if ((tid & 63) == 0) part[tid >> 6] = v;
    __syncthreads();
    if (tid == 0)
        out[0] = part[0] + part[1] + part[2] + part[3];
}

extern "C" void kernel_launch(void* const* d_in, const int* in_sizes, int n_in,
                              void* d_out, int out_size, void* d_ws, size_t ws_size,
                              hipStream_t stream) {
    const float* inputs_ref   = (const float*)d_in[0];
    const float* inputs_other = (const float*)d_in[1];
    const float* weights      = (const float*)d_in[2];
    const int*   inds_ref     = (const int*)d_in[3];
    const int*   inds_other   = (const int*)d_in[4];
    const int*   rand_inds    = (const int*)d_in[5];
    float* out = (float*)d_out;

    // workspace layout: Fr [B][N][C], Fo [B][N][C] (2 MB each), partials 8 KB
    float* Fr = (float*)d_ws;
    float* Fo = Fr + (size_t)BB * NN * CC;
    float* partials = Fo + (size_t)BB * NN * CC;

    // pass 1: 2(sel)*2(b)*64(g)*4(chunk) = 1024 waves -> 256 blocks
    gather_kernel<<<256, 256, 0, stream>>>(
        inputs_ref, inputs_other, inds_ref, inds_other, Fr, Fo);

    // pass 2: B*N = 8192 waves -> 2048 blocks, per-block partials
    loss_kernel<<<2048, 256, 0, stream>>>(
        Fr, Fo, weights, inds_ref, rand_inds, partials);

    // pass 3: single-block tree reduction -> out[0]
    reduce_kernel<<<1, 256, 0, stream>>>(partials, 2048, out);
}